// Round 1
// 1056.821 us; speedup vs baseline: 1.0243x; 1.0243x over previous
//
#include <hip/hip_runtime.h>

typedef float f32x4 __attribute__((ext_vector_type(4)));
typedef short short8v __attribute__((ext_vector_type(8)));

__device__ __forceinline__ float bf2f(unsigned short h) {
  union { unsigned int u; float f; } v; v.u = ((unsigned int)h) << 16; return v.f;
}
__device__ __forceinline__ unsigned short f2bf(float f) {
  union { float f; unsigned int u; } v; v.f = f;
  unsigned int u = v.u;
  return (unsigned short)((u + 0x7fffu + ((u >> 16) & 1u)) >> 16);
}
// load 8 consecutive f32, round to bf16 MFMA fragment
__device__ __forceinline__ short8v ld8f(const float* __restrict__ p) {
  f32x4 a = *(const f32x4*)p;
  f32x4 b = *(const f32x4*)(p + 4);
  short8v r;
  r[0] = (short)f2bf(a[0]); r[1] = (short)f2bf(a[1]);
  r[2] = (short)f2bf(a[2]); r[3] = (short)f2bf(a[3]);
  r[4] = (short)f2bf(b[0]); r[5] = (short)f2bf(b[1]);
  r[6] = (short)f2bf(b[2]); r[7] = (short)f2bf(b[3]);
  return r;
}
// weight fragment loader: BF16W=1 -> direct bf16 load from prepass buffer
template<int B>
__device__ __forceinline__ short8v ldw(const float* __restrict__ wf,
                                       const unsigned short* __restrict__ wb, int off) {
  if constexpr (B != 0) {
    return *(const short8v*)(wb + off);
  } else {
    return ld8f(wf + off);
  }
}

// btab[h][225] = 16*sigmoid( relu(table@w1^T + b1) @ w2^T )   (all f32)
__global__ void cpb_kernel(const float* __restrict__ w1, const float* __restrict__ b1,
                           const float* __restrict__ w2, float* __restrict__ btab) {
  __shared__ float h1s[512];
  int t = threadIdx.x;
  int i = blockIdx.x;            // 0..224
  int a = i / 15, b = i % 15;
  float va = (float)(a - 7) * (8.0f / 7.0f);
  float vb = (float)(b - 7) * (8.0f / 7.0f);
  float tx = copysignf(log2f(fabsf(va) + 1.0f) * (1.0f / 3.0f), va);
  float ty = copysignf(log2f(fabsf(vb) + 1.0f) * (1.0f / 3.0f), vb);
  float h = tx * w1[2 * t] + ty * w1[2 * t + 1] + b1[t];
  h1s[t] = fmaxf(h, 0.0f);
  __syncthreads();
  int head = t >> 6, lane = t & 63;
  float s = 0.f;
  for (int j = lane; j < 512; j += 64) s += h1s[j] * w2[head * 512 + j];
  #pragma unroll
  for (int m = 1; m < 64; m <<= 1) s += __shfl_xor(s, m, 64);
  if (lane == 0) btab[head * 225 + i] = 16.0f / (1.0f + __expf(-s));
}

// prepass: convert wq,wk,wv,wo (each [256][256] f32) to bf16 at dst (262144 shorts)
__global__ void wconv_kernel(const float* __restrict__ wq, const float* __restrict__ wk,
                             const float* __restrict__ wv, const float* __restrict__ wo,
                             unsigned short* __restrict__ dst) {
  int i = (blockIdx.x * 256 + threadIdx.x) * 8;   // grid 128 x 256 -> 262144 elems
  const float* src; int j;
  if (i < 65536)       { src = wq; j = i; }
  else if (i < 131072) { src = wk; j = i - 65536; }
  else if (i < 196608) { src = wv; j = i - 131072; }
  else                 { src = wo; j = i - 196608; }
  short8v v = ld8f(src + j);
  *(short8v*)(dst + i) = v;
}

// LDS: single shared O/Z buffer [64 tok][264 ch] bf16 = 33792 B -> 4 blocks/CU.
// Per-wave: everything else (Q,K,V,S,P) lives in registers via the C-layout
// transpose trick: mfma(Wfrag, xfrag) -> D[outch][tok]; lane(quad,l16) holds
// (outch = mtile*16+quad*4+r, tok = nt*16+l16), which reinterpreted IS the
// A/B-fragment [m=tok(l16)][k-pos=quad*8+j] with channel perm
// pi(quad*8+j) = (j<4 ? quad*4+j : 16+quad*4+(j-4)) shared by Q and K
// (perm cancels in the dot product). Same trick pairs P^T and V on tok_k.
template<int BF16W>
__global__ __launch_bounds__(256, 4)
void swin_kernel(const float* __restrict__ img,
                 const float* __restrict__ wq, const float* __restrict__ bq,
                 const float* __restrict__ wk, const float* __restrict__ bk,
                 const float* __restrict__ wv, const float* __restrict__ bv,
                 const float* __restrict__ wo, const float* __restrict__ bo,
                 const float* __restrict__ ls,
                 const float* __restrict__ btab_g,
                 const unsigned short* __restrict__ wbf,
                 float* __restrict__ out) {
  __shared__ __align__(16) unsigned short Os[64 * 264];
  const int tid = threadIdx.x;
  const int wave = tid >> 6, lane = tid & 63;
  const int quad = lane >> 4, l16 = lane & 15;
  const int bid = blockIdx.x;
  const int bimg = bid >> 2, w = bid & 3;
  const int wr = (w >> 1) * 8, wc = (w & 1) * 8;
  const bool wrh = (w & 2) != 0, wch = (w & 1) != 0;

  const unsigned short* wbq = wbf;
  const unsigned short* wbk = wbf + 65536;
  const unsigned short* wbv = wbf + 131072;
  const unsigned short* wbo = wbf + 196608;

  int pixbase[4];
  #pragma unroll
  for (int mt = 0; mt < 4; ++mt) {
    int t = mt * 16 + l16;
    int pi = (wr + (t >> 3) + 12) & 15;
    int pj = (wc + (t & 7) + 12) & 15;
    pixbase[mt] = (bimg * 256 + pi * 16 + pj) * 256;
  }

  const f32x4 zf4 = {0.f, 0.f, 0.f, 0.f};

  #pragma unroll 1
  for (int hh = 0; hh < 2; ++hh) {
    const int h = wave * 2 + hh;
    const float scale = __expf(fminf(ls[h], 4.60517019f));

    // ---- pass 1: Q,K accumulate (D[outch][tok]) ----
    f32x4 qac[2][4], kac[2][4];   // [outch mtile][tok ntile]
    #pragma unroll
    for (int mtile = 0; mtile < 2; ++mtile)
      #pragma unroll
      for (int nt = 0; nt < 4; ++nt) { qac[mtile][nt] = zf4; kac[mtile][nt] = zf4; }
    #pragma unroll
    for (int kt = 0; kt < 8; ++kt) {
      short8v xk[4], wqf[2], wkf[2];
      #pragma unroll
      for (int mt = 0; mt < 4; ++mt)
        xk[mt] = ld8f(img + pixbase[mt] + kt * 32 + quad * 8);
      #pragma unroll
      for (int mtile = 0; mtile < 2; ++mtile) {
        int off = (h * 32 + mtile * 16 + l16) * 256 + kt * 32 + quad * 8;
        wqf[mtile] = ldw<BF16W>(wq, wbq, off);
        wkf[mtile] = ldw<BF16W>(wk, wbk, off);
      }
      #pragma unroll
      for (int mtile = 0; mtile < 2; ++mtile)
        #pragma unroll
        for (int nt = 0; nt < 4; ++nt) {
          qac[mtile][nt] = __builtin_amdgcn_mfma_f32_16x16x32_bf16(wqf[mtile], xk[nt], qac[mtile][nt], 0, 0, 0);
          kac[mtile][nt] = __builtin_amdgcn_mfma_f32_16x16x32_bf16(wkf[mtile], xk[nt], kac[mtile][nt], 0, 0, 0);
        }
    }

    // ---- bias + per-token norms (8 in-reg + shfl 16/32) + fold + bf16 frags ----
    float bqv[2][4], bkv[2][4];
    #pragma unroll
    for (int mtile = 0; mtile < 2; ++mtile)
      #pragma unroll
      for (int r = 0; r < 4; ++r) {
        bqv[mtile][r] = bq[h * 32 + mtile * 16 + quad * 4 + r];
        bkv[mtile][r] = bk[h * 32 + mtile * 16 + quad * 4 + r];
      }
    short8v qf[4], kf[4];
    #pragma unroll
    for (int nt = 0; nt < 4; ++nt) {
      float sq = 0.f, sk = 0.f;
      #pragma unroll
      for (int mtile = 0; mtile < 2; ++mtile)
        #pragma unroll
        for (int r = 0; r < 4; ++r) {
          float qv = qac[mtile][nt][r] + bqv[mtile][r];
          float kv = kac[mtile][nt][r] + bkv[mtile][r];
          qac[mtile][nt][r] = qv; kac[mtile][nt][r] = kv;
          sq += qv * qv; sk += kv * kv;
        }
      sq += __shfl_xor(sq, 16); sq += __shfl_xor(sq, 32);
      sk += __shfl_xor(sk, 16); sk += __shfl_xor(sk, 32);
      float rqv = rsqrtf(fmaxf(sq, 1e-24f)) * scale;
      float rkv = rsqrtf(fmaxf(sk, 1e-24f));
      #pragma unroll
      for (int mtile = 0; mtile < 2; ++mtile)
        #pragma unroll
        for (int r = 0; r < 4; ++r) {
          qf[nt][mtile * 4 + r] = (short)f2bf(qac[mtile][nt][r] * rqv);
          kf[nt][mtile * 4 + r] = (short)f2bf(kac[mtile][nt][r] * rkv);
        }
    }

    // ---- per-lane key-side precompute: tok_k = mtk*16 + quad*4 + r ----
    int kk[16];
    #pragma unroll
    for (int mtk = 0; mtk < 4; ++mtk)
      #pragma unroll
      for (int r = 0; r < 4; ++r) {
        int tk = mtk * 16 + quad * 4 + r;
        int ki = tk >> 3, kj = tk & 7;
        int kgr = wrh ? (ki < 4 ? 1 : 2) : 0;
        int kgc = wch ? (kj < 4 ? 1 : 2) : 0;
        kk[mtk * 4 + r] = (112 - ki * 15 - kj) | (kgr << 8) | (kgc << 10);
      }
    const float* bg = btab_g + h * 225;

    // ---- per ntq: S^T tile, bias+mask+softmax over rows(tok_k), P frags ----
    short8v pf[4][2];
    #pragma unroll
    for (int ntq = 0; ntq < 4; ++ntq) {
      f32x4 st[4];
      #pragma unroll
      for (int mtk = 0; mtk < 4; ++mtk)
        st[mtk] = __builtin_amdgcn_mfma_f32_16x16x32_bf16(kf[mtk], qf[ntq], zf4, 0, 0, 0);
      int tq = ntq * 16 + l16;
      int qi = tq >> 3, qj = tq & 7;
      int qo = qi * 15 + qj;
      int qgr = wrh ? (qi < 4 ? 1 : 2) : 0;
      int qgc = wch ? (qj < 4 ? 1 : 2) : 0;
      float mx = -30000.f;
      #pragma unroll
      for (int mtk = 0; mtk < 4; ++mtk)
        #pragma unroll
        for (int r = 0; r < 4; ++r) {
          int kv = kk[mtk * 4 + r];
          float val = st[mtk][r] + bg[qo + (kv & 255)];
          if ((((kv >> 8) & 3) != qgr) || (((kv >> 10) & 3) != qgc)) val = -30000.f;
          st[mtk][r] = val;
          mx = fmaxf(mx, val);
        }
      mx = fmaxf(mx, __shfl_xor(mx, 16)); mx = fmaxf(mx, __shfl_xor(mx, 32));
      float sum = 0.f;
      #pragma unroll
      for (int mtk = 0; mtk < 4; ++mtk)
        #pragma unroll
        for (int r = 0; r < 4; ++r) {
          float p = __expf(st[mtk][r] - mx);
          st[mtk][r] = p; sum += p;
        }
      sum += __shfl_xor(sum, 16); sum += __shfl_xor(sum, 32);
      float rs = 1.0f / sum;
      #pragma unroll
      for (int pair = 0; pair < 2; ++pair)
        #pragma unroll
        for (int j = 0; j < 8; ++j)
          pf[ntq][pair][j] = (short)f2bf(st[pair * 2 + (j >> 2)][j & 3] * rs);
    }

    // ---- pass 2: V accumulate (D[tok][ch]) ----
    f32x4 vac[4][2];   // [tok mtile][ch ntile]
    #pragma unroll
    for (int mt = 0; mt < 4; ++mt)
      #pragma unroll
      for (int nt2 = 0; nt2 < 2; ++nt2) vac[mt][nt2] = zf4;
    #pragma unroll
    for (int kt = 0; kt < 8; ++kt) {
      short8v xk[4], wvf[2];
      #pragma unroll
      for (int mt = 0; mt < 4; ++mt)
        xk[mt] = ld8f(img + pixbase[mt] + kt * 32 + quad * 8);
      #pragma unroll
      for (int nt2 = 0; nt2 < 2; ++nt2) {
        int off = (h * 32 + nt2 * 16 + l16) * 256 + kt * 32 + quad * 8;
        wvf[nt2] = ldw<BF16W>(wv, wbv, off);
      }
      #pragma unroll
      for (int mt = 0; mt < 4; ++mt)
        #pragma unroll
        for (int nt2 = 0; nt2 < 2; ++nt2)
          vac[mt][nt2] = __builtin_amdgcn_mfma_f32_16x16x32_bf16(xk[mt], wvf[nt2], vac[mt][nt2], 0, 0, 0);
    }
    float bv0 = bv[h * 32 + l16];
    float bv1 = bv[h * 32 + 16 + l16];
    short8v vf[2][2];   // [tok pair][ch ntile] as B-frag [n=ch][k=tok]
    #pragma unroll
    for (int pair = 0; pair < 2; ++pair)
      #pragma unroll
      for (int nt2 = 0; nt2 < 2; ++nt2)
        #pragma unroll
        for (int j = 0; j < 8; ++j)
          vf[pair][nt2][j] = (short)f2bf(vac[2 * pair + (j >> 2)][nt2][j & 3] + (nt2 ? bv1 : bv0));

    // ---- O = P.V, stage to shared Os[tok][ch] ----
    #pragma unroll
    for (int ntq = 0; ntq < 4; ++ntq)
      #pragma unroll
      for (int nt2 = 0; nt2 < 2; ++nt2) {
        f32x4 o = __builtin_amdgcn_mfma_f32_16x16x32_bf16(pf[ntq][0], vf[0][nt2], zf4, 0, 0, 0);
        o = __builtin_amdgcn_mfma_f32_16x16x32_bf16(pf[ntq][1], vf[1][nt2], o, 0, 0, 0);
        #pragma unroll
        for (int r = 0; r < 4; ++r)
          Os[(ntq * 16 + quad * 4 + r) * 264 + h * 32 + nt2 * 16 + l16] = f2bf(o[r]);
      }
  } // hh

  __syncthreads();

  // ---- Z = O @ wo^T, wave owns out-channels [wave*64, wave*64+64) ----
  f32x4 z[4][4];
  #pragma unroll
  for (int mt = 0; mt < 4; ++mt)
    #pragma unroll
    for (int nt = 0; nt < 4; ++nt) z[mt][nt] = zf4;
  #pragma unroll
  for (int kt = 0; kt < 8; ++kt) {   // kt = head (32 k-channels)
    short8v oa[4];
    #pragma unroll
    for (int mt = 0; mt < 4; ++mt)
      oa[mt] = *(const short8v*)(Os + (mt * 16 + l16) * 264 + kt * 32 + quad * 8);
    #pragma unroll
    for (int nt = 0; nt < 4; ++nt) {
      int off = (wave * 64 + nt * 16 + l16) * 256 + kt * 32 + quad * 8;
      short8v wb = ldw<BF16W>(wo, wbo, off);
      #pragma unroll
      for (int mt = 0; mt < 4; ++mt)
        z[mt][nt] = __builtin_amdgcn_mfma_f32_16x16x32_bf16(oa[mt], wb, z[mt][nt], 0, 0, 0);
    }
  }
  __syncthreads();

  // ---- Z -> LDS staging (overlay Os), + bo ----
  #pragma unroll
  for (int nt = 0; nt < 4; ++nt) {
    int col = wave * 64 + nt * 16 + l16;
    float bov = bo[col];
    #pragma unroll
    for (int mt = 0; mt < 4; ++mt)
      #pragma unroll
      for (int r = 0; r < 4; ++r)
        Os[(mt * 16 + quad * 4 + r) * 264 + col] = f2bf(z[mt][nt][r] + bov);
  }
  __syncthreads();

  // ---- coalesced f32 store, inverse roll ----
  #pragma unroll
  for (int p8 = 0; p8 < 8; ++p8) {
    int p = p8 * 8 + (tid >> 5);
    int ch = (tid & 31) * 8;
    const unsigned short* zp = Os + p * 264 + ch;
    short8v vv = *(const short8v*)zp;
    f32x4 o0, o1;
    o0[0] = bf2f((unsigned short)vv[0]); o0[1] = bf2f((unsigned short)vv[1]);
    o0[2] = bf2f((unsigned short)vv[2]); o0[3] = bf2f((unsigned short)vv[3]);
    o1[0] = bf2f((unsigned short)vv[4]); o1[1] = bf2f((unsigned short)vv[5]);
    o1[2] = bf2f((unsigned short)vv[6]); o1[3] = bf2f((unsigned short)vv[7]);
    int pi = (wr + (p >> 3) + 12) & 15;
    int pj = (wc + (p & 7) + 12) & 15;
    float* op = out + (bimg * 256 + pi * 16 + pj) * 256 + ch;
    *(f32x4*)op = o0;
    *(f32x4*)(op + 4) = o1;
  }
}

extern "C" void kernel_launch(void* const* d_in, const int* in_sizes, int n_in,
                              void* d_out, int out_size, void* d_ws, size_t ws_size,
                              hipStream_t stream) {
  (void)in_sizes; (void)n_in; (void)out_size;
  const float* img = (const float*)d_in[0];
  const float* wq  = (const float*)d_in[1];
  const float* bq  = (const float*)d_in[2];
  const float* wk  = (const float*)d_in[3];
  const float* bk  = (const float*)d_in[4];
  const float* wv  = (const float*)d_in[5];
  const float* bv  = (const float*)d_in[6];
  const float* wo  = (const float*)d_in[7];
  const float* bo  = (const float*)d_in[8];
  const float* ls  = (const float*)d_in[9];
  const float* w1  = (const float*)d_in[10];
  const float* b1  = (const float*)d_in[11];
  const float* w2  = (const float*)d_in[12];
  float* out = (float*)d_out;
  float* btab = (float*)d_ws;   // 1800 floats

  cpb_kernel<<<225, 512, 0, stream>>>(w1, b1, w2, btab);

  const size_t need = 8192 + 4 * 65536 * sizeof(unsigned short);  // btab pad + 4 bf16 matrices
  if (ws_size >= need) {
    unsigned short* wbf = (unsigned short*)((char*)d_ws + 8192);
    wconv_kernel<<<128, 256, 0, stream>>>(wq, wk, wv, wo, wbf);
    swin_kernel<1><<<2048, 256, 0, stream>>>(img, wq, bq, wk, bk, wv, bv, wo, bo,
                                             ls, btab, wbf, out);
  } else {
    swin_kernel<0><<<2048, 256, 0, stream>>>(img, wq, bq, wk, bk, wv, bv, wo, bo,
                                             ls, btab, (const unsigned short*)nullptr, out);
  }
}

// Round 2
// 535.203 us; speedup vs baseline: 2.0227x; 1.9746x over previous
//
#include <hip/hip_runtime.h>

typedef float f32x4 __attribute__((ext_vector_type(4)));
typedef short short8v __attribute__((ext_vector_type(8)));

__device__ __forceinline__ unsigned int cvtpk(float lo, float hi) {
  unsigned int r;
  asm("v_cvt_pk_bf16_f32 %0, %1, %2" : "=v"(r) : "v"(lo), "v"(hi));
  return r;
}
__device__ __forceinline__ float bf2f(unsigned short h) {
  union { unsigned int u; float f; } v; v.u = ((unsigned int)h) << 16; return v.f;
}
__device__ __forceinline__ unsigned short f2bf(float f) {
  return (unsigned short)cvtpk(f, f);
}
union S8 { short8v s; unsigned int u[4]; };

// load 8 consecutive f32, round to bf16 MFMA fragment (4x v_cvt_pk_bf16_f32)
__device__ __forceinline__ short8v ld8f(const float* __restrict__ p) {
  f32x4 a = *(const f32x4*)p;
  f32x4 b = *(const f32x4*)(p + 4);
  S8 r;
  r.u[0] = cvtpk(a[0], a[1]);
  r.u[1] = cvtpk(a[2], a[3]);
  r.u[2] = cvtpk(b[0], b[1]);
  r.u[3] = cvtpk(b[2], b[3]);
  return r.s;
}
// weight fragment loader: BF16W=1 -> direct bf16 load from prepass buffer
template<int B>
__device__ __forceinline__ short8v ldw(const float* __restrict__ wf,
                                       const unsigned short* __restrict__ wb, int off) {
  if constexpr (B != 0) {
    return *(const short8v*)(wb + off);
  } else {
    return ld8f(wf + off);
  }
}

// btab[h][225] = 16*sigmoid( relu(table@w1^T + b1) @ w2^T )   (all f32)
__global__ void cpb_kernel(const float* __restrict__ w1, const float* __restrict__ b1,
                           const float* __restrict__ w2, float* __restrict__ btab) {
  __shared__ float h1s[512];
  int t = threadIdx.x;
  int i = blockIdx.x;            // 0..224
  int a = i / 15, b = i % 15;
  float va = (float)(a - 7) * (8.0f / 7.0f);
  float vb = (float)(b - 7) * (8.0f / 7.0f);
  float tx = copysignf(log2f(fabsf(va) + 1.0f) * (1.0f / 3.0f), va);
  float ty = copysignf(log2f(fabsf(vb) + 1.0f) * (1.0f / 3.0f), vb);
  float h = tx * w1[2 * t] + ty * w1[2 * t + 1] + b1[t];
  h1s[t] = fmaxf(h, 0.0f);
  __syncthreads();
  int head = t >> 6, lane = t & 63;
  float s = 0.f;
  for (int j = lane; j < 512; j += 64) s += h1s[j] * w2[head * 512 + j];
  #pragma unroll
  for (int m = 1; m < 64; m <<= 1) s += __shfl_xor(s, m, 64);
  if (lane == 0) btab[head * 225 + i] = 16.0f / (1.0f + __expf(-s));
}

// prepass: convert wq,wk,wv,wo (each [256][256] f32) to bf16 at dst (262144 shorts)
__global__ void wconv_kernel(const float* __restrict__ wq, const float* __restrict__ wk,
                             const float* __restrict__ wv, const float* __restrict__ wo,
                             unsigned short* __restrict__ dst) {
  int i = (blockIdx.x * 256 + threadIdx.x) * 8;   // grid 128 x 256 -> 262144 elems
  const float* src; int j;
  if (i < 65536)       { src = wq; j = i; }
  else if (i < 131072) { src = wk; j = i - 65536; }
  else if (i < 196608) { src = wv; j = i - 131072; }
  else                 { src = wo; j = i - 196608; }
  short8v v = ld8f(src + j);
  *(short8v*)(dst + i) = v;
}

// LDS: single shared O/Z buffer [64 tok][264 ch] bf16 = 33792 B.
// Register plan (anti-spill): per phase, accumulators <=64 regs (AGPR side);
// fragments qf/kf/vf = 48 arch regs persistent; P fused into PV per ntq so it
// never fully materializes; mask/bias indices computed from 2 per-lane scalars.
template<int BF16W>
__global__ __launch_bounds__(256, 3)
void swin_kernel(const float* __restrict__ img,
                 const float* __restrict__ wq, const float* __restrict__ bq,
                 const float* __restrict__ wk, const float* __restrict__ bk,
                 const float* __restrict__ wv, const float* __restrict__ bv,
                 const float* __restrict__ wo, const float* __restrict__ bo,
                 const float* __restrict__ ls,
                 const float* __restrict__ btab_g,
                 const unsigned short* __restrict__ wbf,
                 float* __restrict__ out) {
  __shared__ __align__(16) unsigned short Os[64 * 264];
  const int tid = threadIdx.x;
  const int wave = tid >> 6, lane = tid & 63;
  const int quad = lane >> 4, l16 = lane & 15;
  const int bid = blockIdx.x;
  const int bimg = bid >> 2, w = bid & 3;
  const int wr = (w >> 1) * 8, wc = (w & 1) * 8;
  const bool wrh = (w & 2) != 0, wch = (w & 1) != 0;

  const unsigned short* wbq = wbf;
  const unsigned short* wbk = wbf + 65536;
  const unsigned short* wbv = wbf + 131072;
  const unsigned short* wbo = wbf + 196608;

  int pixbase[4];
  #pragma unroll
  for (int mt = 0; mt < 4; ++mt) {
    int t = mt * 16 + l16;
    int pi = (wr + (t >> 3) + 12) & 15;
    int pj = (wc + (t & 7) + 12) & 15;
    pixbase[mt] = (bimg * 256 + pi * 16 + pj) * 256;
  }

  // bias-table gather index = (qbase + 30*ntq) + (koff - 30*mtk - r); all in [0,224]
  const int qbase = 15 * (l16 >> 3) + (l16 & 7);
  const int koff  = 112 - 15 * (quad >> 1) - 4 * (quad & 1);
  // column mask term: qgc != kgc  <=>  wch && (bit2(l16) ^ bit0(quad))
  const bool cmaskb = wch && ((((l16 >> 2) ^ quad) & 1) != 0);

  const f32x4 zf4 = {0.f, 0.f, 0.f, 0.f};

  #pragma unroll 1
  for (int hh = 0; hh < 2; ++hh) {
    const int h = wave * 2 + hh;
    const float scale = __expf(fminf(ls[h], 4.60517019f));

    // ---- pass 1: Q,K accumulate (D[outch][tok]) ----
    f32x4 qac[2][4], kac[2][4];   // [outch mtile][tok ntile]
    #pragma unroll
    for (int mtile = 0; mtile < 2; ++mtile)
      #pragma unroll
      for (int nt = 0; nt < 4; ++nt) { qac[mtile][nt] = zf4; kac[mtile][nt] = zf4; }
    #pragma unroll
    for (int kt = 0; kt < 8; ++kt) {
      short8v xk[4], wqf[2], wkf[2];
      #pragma unroll
      for (int mt = 0; mt < 4; ++mt)
        xk[mt] = ld8f(img + pixbase[mt] + kt * 32 + quad * 8);
      #pragma unroll
      for (int mtile = 0; mtile < 2; ++mtile) {
        int off = (h * 32 + mtile * 16 + l16) * 256 + kt * 32 + quad * 8;
        wqf[mtile] = ldw<BF16W>(wq, wbq, off);
        wkf[mtile] = ldw<BF16W>(wk, wbk, off);
      }
      #pragma unroll
      for (int mtile = 0; mtile < 2; ++mtile)
        #pragma unroll
        for (int nt = 0; nt < 4; ++nt) {
          qac[mtile][nt] = __builtin_amdgcn_mfma_f32_16x16x32_bf16(wqf[mtile], xk[nt], qac[mtile][nt], 0, 0, 0);
          kac[mtile][nt] = __builtin_amdgcn_mfma_f32_16x16x32_bf16(wkf[mtile], xk[nt], kac[mtile][nt], 0, 0, 0);
        }
    }

    // ---- bias + per-token norms (8 in-reg + shfl 16/32) + fold + bf16 frags ----
    float bqv[2][4], bkv[2][4];
    #pragma unroll
    for (int mtile = 0; mtile < 2; ++mtile)
      #pragma unroll
      for (int r = 0; r < 4; ++r) {
        bqv[mtile][r] = bq[h * 32 + mtile * 16 + quad * 4 + r];
        bkv[mtile][r] = bk[h * 32 + mtile * 16 + quad * 4 + r];
      }
    short8v qf[4], kf[4];
    #pragma unroll
    for (int nt = 0; nt < 4; ++nt) {
      float sq = 0.f, sk = 0.f;
      #pragma unroll
      for (int mtile = 0; mtile < 2; ++mtile)
        #pragma unroll
        for (int r = 0; r < 4; ++r) {
          float qv = qac[mtile][nt][r] + bqv[mtile][r];
          float kv = kac[mtile][nt][r] + bkv[mtile][r];
          qac[mtile][nt][r] = qv; kac[mtile][nt][r] = kv;
          sq += qv * qv; sk += kv * kv;
        }
      sq += __shfl_xor(sq, 16); sq += __shfl_xor(sq, 32);
      sk += __shfl_xor(sk, 16); sk += __shfl_xor(sk, 32);
      float rqv = rsqrtf(fmaxf(sq, 1e-24f)) * scale;
      float rkv = rsqrtf(fmaxf(sk, 1e-24f));
      S8 uq, uk;
      uq.u[0] = cvtpk(qac[0][nt][0] * rqv, qac[0][nt][1] * rqv);
      uq.u[1] = cvtpk(qac[0][nt][2] * rqv, qac[0][nt][3] * rqv);
      uq.u[2] = cvtpk(qac[1][nt][0] * rqv, qac[1][nt][1] * rqv);
      uq.u[3] = cvtpk(qac[1][nt][2] * rqv, qac[1][nt][3] * rqv);
      uk.u[0] = cvtpk(kac[0][nt][0] * rkv, kac[0][nt][1] * rkv);
      uk.u[1] = cvtpk(kac[0][nt][2] * rkv, kac[0][nt][3] * rkv);
      uk.u[2] = cvtpk(kac[1][nt][0] * rkv, kac[1][nt][1] * rkv);
      uk.u[3] = cvtpk(kac[1][nt][2] * rkv, kac[1][nt][3] * rkv);
      qf[nt] = uq.s; kf[nt] = uk.s;
    }

    // ---- pass 2: V accumulate (D[tok][ch]) ----
    f32x4 vac[4][2];   // [tok mtile][ch ntile]
    #pragma unroll
    for (int mt = 0; mt < 4; ++mt)
      #pragma unroll
      for (int nt2 = 0; nt2 < 2; ++nt2) vac[mt][nt2] = zf4;
    #pragma unroll
    for (int kt = 0; kt < 8; ++kt) {
      short8v xk[4], wvf[2];
      #pragma unroll
      for (int mt = 0; mt < 4; ++mt)
        xk[mt] = ld8f(img + pixbase[mt] + kt * 32 + quad * 8);
      #pragma unroll
      for (int nt2 = 0; nt2 < 2; ++nt2) {
        int off = (h * 32 + nt2 * 16 + l16) * 256 + kt * 32 + quad * 8;
        wvf[nt2] = ldw<BF16W>(wv, wbv, off);
      }
      #pragma unroll
      for (int mt = 0; mt < 4; ++mt)
        #pragma unroll
        for (int nt2 = 0; nt2 < 2; ++nt2)
          vac[mt][nt2] = __builtin_amdgcn_mfma_f32_16x16x32_bf16(xk[mt], wvf[nt2], vac[mt][nt2], 0, 0, 0);
    }
    float bv0 = bv[h * 32 + l16];
    float bv1 = bv[h * 32 + 16 + l16];
    short8v vf[2][2];   // [tok pair][ch ntile] as B-frag [n=ch][k=tok]
    #pragma unroll
    for (int pair = 0; pair < 2; ++pair)
      #pragma unroll
      for (int nt2 = 0; nt2 < 2; ++nt2) {
        float bb = nt2 ? bv1 : bv0;
        S8 u;
        u.u[0] = cvtpk(vac[2 * pair][nt2][0] + bb, vac[2 * pair][nt2][1] + bb);
        u.u[1] = cvtpk(vac[2 * pair][nt2][2] + bb, vac[2 * pair][nt2][3] + bb);
        u.u[2] = cvtpk(vac[2 * pair + 1][nt2][0] + bb, vac[2 * pair + 1][nt2][1] + bb);
        u.u[3] = cvtpk(vac[2 * pair + 1][nt2][2] + bb, vac[2 * pair + 1][nt2][3] + bb);
        vf[pair][nt2] = u.s;
      }

    // ---- fused per-ntq: S^T tile -> softmax -> P frag -> PV -> Os ----
    const float* bg = btab_g + h * 225;
    #pragma unroll
    for (int ntq = 0; ntq < 4; ++ntq) {
      f32x4 st[4];
      #pragma unroll
      for (int mtk = 0; mtk < 4; ++mtk)
        st[mtk] = __builtin_amdgcn_mfma_f32_16x16x32_bf16(kf[mtk], qf[ntq], zf4, 0, 0, 0);
      const float* bgq = bg + qbase + 30 * ntq + koff;
      const bool rmA = wrh && (ntq >= 2);   // row mask for mtk<2
      const bool rmB = wrh && (ntq < 2);    // row mask for mtk>=2
      float mx = -30000.f;
      #pragma unroll
      for (int mtk = 0; mtk < 4; ++mtk) {
        const bool rm = (mtk < 2) ? rmA : rmB;
        #pragma unroll
        for (int r = 0; r < 4; ++r) {
          float val = st[mtk][r] + bgq[-30 * mtk - r];
          if (rm || cmaskb) val = -30000.f;
          st[mtk][r] = val;
          mx = fmaxf(mx, val);
        }
      }
      mx = fmaxf(mx, __shfl_xor(mx, 16)); mx = fmaxf(mx, __shfl_xor(mx, 32));
      float sum = 0.f;
      #pragma unroll
      for (int mtk = 0; mtk < 4; ++mtk)
        #pragma unroll
        for (int r = 0; r < 4; ++r) {
          float p = __expf(st[mtk][r] - mx);
          st[mtk][r] = p; sum += p;
        }
      sum += __shfl_xor(sum, 16); sum += __shfl_xor(sum, 32);
      float rs = 1.0f / sum;
      S8 p0, p1;
      p0.u[0] = cvtpk(st[0][0] * rs, st[0][1] * rs);
      p0.u[1] = cvtpk(st[0][2] * rs, st[0][3] * rs);
      p0.u[2] = cvtpk(st[1][0] * rs, st[1][1] * rs);
      p0.u[3] = cvtpk(st[1][2] * rs, st[1][3] * rs);
      p1.u[0] = cvtpk(st[2][0] * rs, st[2][1] * rs);
      p1.u[1] = cvtpk(st[2][2] * rs, st[2][3] * rs);
      p1.u[2] = cvtpk(st[3][0] * rs, st[3][1] * rs);
      p1.u[3] = cvtpk(st[3][2] * rs, st[3][3] * rs);
      #pragma unroll
      for (int nt2 = 0; nt2 < 2; ++nt2) {
        f32x4 o = __builtin_amdgcn_mfma_f32_16x16x32_bf16(p0.s, vf[0][nt2], zf4, 0, 0, 0);
        o = __builtin_amdgcn_mfma_f32_16x16x32_bf16(p1.s, vf[1][nt2], o, 0, 0, 0);
        #pragma unroll
        for (int r = 0; r < 4; ++r)
          Os[(ntq * 16 + quad * 4 + r) * 264 + h * 32 + nt2 * 16 + l16] = f2bf(o[r]);
      }
    }
  } // hh

  __syncthreads();

  // ---- Z = O @ wo^T, wave owns out-channels [wave*64, wave*64+64) ----
  f32x4 z[4][4];
  #pragma unroll
  for (int mt = 0; mt < 4; ++mt)
    #pragma unroll
    for (int nt = 0; nt < 4; ++nt) z[mt][nt] = zf4;
  #pragma unroll
  for (int kt = 0; kt < 8; ++kt) {   // kt = head (32 k-channels)
    short8v oa[4];
    #pragma unroll
    for (int mt = 0; mt < 4; ++mt)
      oa[mt] = *(const short8v*)(Os + (mt * 16 + l16) * 264 + kt * 32 + quad * 8);
    #pragma unroll
    for (int nt = 0; nt < 4; ++nt) {
      int off = (wave * 64 + nt * 16 + l16) * 256 + kt * 32 + quad * 8;
      short8v wb = ldw<BF16W>(wo, wbo, off);
      #pragma unroll
      for (int mt = 0; mt < 4; ++mt)
        z[mt][nt] = __builtin_amdgcn_mfma_f32_16x16x32_bf16(oa[mt], wb, z[mt][nt], 0, 0, 0);
    }
  }
  __syncthreads();

  // ---- Z -> LDS staging (overlay Os), + bo ----
  #pragma unroll
  for (int nt = 0; nt < 4; ++nt) {
    int col = wave * 64 + nt * 16 + l16;
    float bov = bo[col];
    #pragma unroll
    for (int mt = 0; mt < 4; ++mt)
      #pragma unroll
      for (int r = 0; r < 4; ++r)
        Os[(mt * 16 + quad * 4 + r) * 264 + col] = f2bf(z[mt][nt][r] + bov);
  }
  __syncthreads();

  // ---- coalesced f32 store, inverse roll ----
  #pragma unroll
  for (int p8 = 0; p8 < 8; ++p8) {
    int p = p8 * 8 + (tid >> 5);
    int ch = (tid & 31) * 8;
    const unsigned short* zp = Os + p * 264 + ch;
    short8v vv = *(const short8v*)zp;
    f32x4 o0, o1;
    o0[0] = bf2f((unsigned short)vv[0]); o0[1] = bf2f((unsigned short)vv[1]);
    o0[2] = bf2f((unsigned short)vv[2]); o0[3] = bf2f((unsigned short)vv[3]);
    o1[0] = bf2f((unsigned short)vv[4]); o1[1] = bf2f((unsigned short)vv[5]);
    o1[2] = bf2f((unsigned short)vv[6]); o1[3] = bf2f((unsigned short)vv[7]);
    int pi = (wr + (p >> 3) + 12) & 15;
    int pj = (wc + (p & 7) + 12) & 15;
    float* op = out + (bimg * 256 + pi * 16 + pj) * 256 + ch;
    *(f32x4*)op = o0;
    *(f32x4*)(op + 4) = o1;
  }
}

extern "C" void kernel_launch(void* const* d_in, const int* in_sizes, int n_in,
                              void* d_out, int out_size, void* d_ws, size_t ws_size,
                              hipStream_t stream) {
  (void)in_sizes; (void)n_in; (void)out_size;
  const float* img = (const float*)d_in[0];
  const float* wq  = (const float*)d_in[1];
  const float* bq  = (const float*)d_in[2];
  const float* wk  = (const float*)d_in[3];
  const float* bk  = (const float*)d_in[4];
  const float* wv  = (const float*)d_in[5];
  const float* bv  = (const float*)d_in[6];
  const float* wo  = (const float*)d_in[7];
  const float* bo  = (const float*)d_in[8];
  const float* ls  = (const float*)d_in[9];
  const float* w1  = (const float*)d_in[10];
  const float* b1  = (const float*)d_in[11];
  const float* w2  = (const float*)d_in[12];
  float* out = (float*)d_out;
  float* btab = (float*)d_ws;   // 1800 floats

  cpb_kernel<<<225, 512, 0, stream>>>(w1, b1, w2, btab);

  const size_t need = 8192 + 4 * 65536 * sizeof(unsigned short);  // btab pad + 4 bf16 matrices
  if (ws_size >= need) {
    unsigned short* wbf = (unsigned short*)((char*)d_ws + 8192);
    wconv_kernel<<<128, 256, 0, stream>>>(wq, wk, wv, wo, wbf);
    swin_kernel<1><<<2048, 256, 0, stream>>>(img, wq, bq, wk, bk, wv, bv, wo, bo,
                                             ls, btab, wbf, out);
  } else {
    swin_kernel<0><<<2048, 256, 0, stream>>>(img, wq, bq, wk, bk, wv, bv, wo, bo,
                                             ls, btab, (const unsigned short*)nullptr, out);
  }
}